// Round 4
// baseline (765.822 us; speedup 1.0000x reference)
//
#include <hip/hip_runtime.h>
#include <hip/hip_bf16.h>

// RGCN forward, MI355X. N=100000, E=400000, IN=OUT=256, R=200, B=32.
// Tier A: wgen (L2-blocked) -> hist+feat -> scan -> deg-scan -> scatter(+dlist)
//  -> pipelined per-relation tile GEMMs (4 tiles/block, gather t+1 in flight
//  under MFMA t) writing scaled bf16 msg -> fused self-loop GEMM + dst-CSR
//  aggregation (LDS f32 tile) writing out once. Tiers B/C: atomic fallbacks.

#define NN 100000
#define EE 400000
#define RR 200
#define BB 32
#define MAXTILES 6464   // >= E/64 + R ; divisible by 32
#define TPB 4
#define EGRID (MAXTILES / TPB)   // 1616
#define EQ (EGRID / 8)           // 202
#define SCHUNK 2048
#define NSCAN ((NN + 255) / 256) // 391

typedef __attribute__((ext_vector_type(8))) short short8v;   // 8 x bf16 (16B)
typedef __attribute__((ext_vector_type(4))) float f32x4;

__device__ __forceinline__ unsigned short f2bf(float f) {
  unsigned u = __float_as_uint(f);
  u += 0x7FFF + ((u >> 16) & 1);          // RNE
  return (unsigned short)(u >> 16);
}
__device__ __forceinline__ float bf2f(unsigned short h) {
  return __uint_as_float(((unsigned)h) << 16);
}

// ---------------------------------------------------------------------------
// Kernel 0: W_pk[r] = bf16(coef[r] @ basis), packed for MFMA B-fragments.
// Layout per relation: [ct=16][kt=8][lane=64][j=8] bf16, where
//   value = W_r[k = kt*32 + (lane>>4)*8 + j][n = ct*16 + (lane&15)].
// Block mapping: XCD x gets ord [x*100,(x+1)*100) = 4 pk8-slices x 25 rgs
// consecutively -> each 256KB basis slice is read once from HBM, 24x from L2.
__global__ __launch_bounds__(256) void k_wgen(const float* __restrict__ basis,
                                              const float* __restrict__ coef,
                                              short* __restrict__ wpk) {
  int b = blockIdx.x;                      // 800 blocks
  int ord = (b & 7) * 100 + (b >> 3);
  int rg = ord % 25;
  int pk8 = (ord / 25) * 256 + threadIdx.x;
  int lane = pk8 & 63;
  int kt = (pk8 >> 6) & 7;
  int ct = pk8 >> 9;
  int n  = ct * 16 + (lane & 15);
  int k0 = kt * 32 + ((lane >> 4) << 3);
  float acc[8][8];
#pragma unroll
  for (int r = 0; r < 8; ++r)
#pragma unroll
    for (int j = 0; j < 8; ++j) acc[r][j] = 0.f;
  for (int bb = 0; bb < BB; ++bb) {
    float bas[8];
#pragma unroll
    for (int j = 0; j < 8; ++j) bas[j] = basis[bb * 65536 + (k0 + j) * 256 + n];
#pragma unroll
    for (int r = 0; r < 8; ++r) {
      float c = coef[(rg * 8 + r) * BB + bb];
#pragma unroll
      for (int j = 0; j < 8; ++j) acc[r][j] += c * bas[j];
    }
  }
#pragma unroll
  for (int r = 0; r < 8; ++r) {
    short8v v;
#pragma unroll
    for (int j = 0; j < 8; ++j) v[j] = (short)f2bf(acc[r][j]);
    *(short8v*)(wpk + (size_t)(rg * 8 + r) * 65536 + (size_t)pk8 * 8) = v;
  }
}

// Kernel 0b: pack self_loop_weight [256][256] f32 into same MFMA layout.
__global__ __launch_bounds__(256) void k_slwpk(const float* __restrict__ slw,
                                               short* __restrict__ spk) {
  int t = blockIdx.x * 256 + threadIdx.x;
  int lane = t & 63;
  int kt = (t >> 6) & 7;
  int ct = t >> 9;
  int n  = ct * 16 + (lane & 15);
  int k0 = kt * 32 + ((lane >> 4) << 3);
  short8v v;
#pragma unroll
  for (int j = 0; j < 8; ++j) v[j] = (short)f2bf(slw[(k0 + j) * 256 + n]);
  *(short8v*)(spk + (size_t)t * 8) = v;
}

// Kernel 1: etype histogram (LDS) + dst in-degree + (FEAT) f32->bf16 convert.
template <bool FEAT>
__global__ __launch_bounds__(256) void k_hist_feat(const int* __restrict__ etype,
                                                   const int* __restrict__ dst,
                                                   const float* __restrict__ in_feat,
                                                   int* __restrict__ hist,
                                                   int* __restrict__ deg,
                                                   unsigned short* __restrict__ featb) {
  __shared__ int lh[RR];
  int tid = threadIdx.x;
  for (int i = tid; i < RR; i += 256) lh[i] = 0;
  __syncthreads();
  for (int e = blockIdx.x * 256 + tid; e < EE; e += gridDim.x * 256) {
    atomicAdd(&lh[etype[e]], 1);
    atomicAdd(&deg[dst[e]], 1);
  }
  if (FEAT) {
    const int total = NN * 64;               // float4 count
    for (int i = blockIdx.x * 256 + tid; i < total; i += gridDim.x * 256) {
      float4 v = ((const float4*)in_feat)[i];
      ushort4 h;
      h.x = f2bf(v.x); h.y = f2bf(v.y); h.z = f2bf(v.z); h.w = f2bf(v.w);
      ((ushort4*)featb)[i] = h;
    }
  }
  __syncthreads();
  for (int i = tid; i < RR; i += 256)
    if (lh[i]) atomicAdd(&hist[i], lh[i]);
}

// Kernel 2 (single block): scan 200 etype bins, emit tile descs, init cursors.
__global__ __launch_bounds__(256) void k_scan(const int* __restrict__ hist,
                                              int* __restrict__ cur,
                                              int4* __restrict__ tdesc) {
  __shared__ int h[RR];
  __shared__ int off[RR];
  __shared__ int toff[RR];
  __shared__ int tot;
  int tid = threadIdx.x;
  for (int i = tid; i < RR; i += 256) h[i] = hist[i];
  __syncthreads();
  if (tid == 0) {
    int s = 0, ts = 0;
    for (int r = 0; r < RR; ++r) {
      off[r] = s; s += h[r];
      toff[r] = ts; ts += (h[r] + 63) >> 6;
    }
    tot = ts;
  }
  __syncthreads();
  if (tid < RR) {
    int r = tid, cnt = h[r], base = off[r], to = toff[r];
    cur[r] = base;
    int nt = (cnt + 63) >> 6;
    for (int t2 = 0; t2 < nt; ++t2)
      tdesc[to + t2] = make_int4(r, base + t2 * 64, min(64, cnt - t2 * 64), 0);
  }
  for (int i = tot + tid; i < MAXTILES; i += 256)
    tdesc[i] = make_int4(0, 0, 0, 0);
}

// --------- dst-CSR build: exclusive scan of deg ----------
__global__ __launch_bounds__(256) void k_dscan_a(const int* __restrict__ deg,
                                                 int* __restrict__ bsum) {
  int i = blockIdx.x * 256 + threadIdx.x;
  int v = (i < NN) ? deg[i] : 0;
#pragma unroll
  for (int d = 32; d; d >>= 1) v += __shfl_down(v, d, 64);
  __shared__ int ws4[4];
  if ((threadIdx.x & 63) == 0) ws4[threadIdx.x >> 6] = v;
  __syncthreads();
  if (threadIdx.x == 0) bsum[blockIdx.x] = ws4[0] + ws4[1] + ws4[2] + ws4[3];
}

__global__ __launch_bounds__(256) void k_dscan_b(int* __restrict__ bsum) {
  __shared__ int l[NSCAN];
  int tid = threadIdx.x;
  for (int i = tid; i < NSCAN; i += 256) l[i] = bsum[i];
  __syncthreads();
  if (tid == 0) {
    int s = 0;
    for (int i = 0; i < NSCAN; ++i) { int t = l[i]; l[i] = s; s += t; }
  }
  __syncthreads();
  for (int i = tid; i < NSCAN; i += 256) bsum[i] = l[i];
}

__global__ __launch_bounds__(256) void k_dscan_c(const int* __restrict__ deg,
                                                 const int* __restrict__ bsum,
                                                 int* __restrict__ row_ptr,
                                                 int* __restrict__ cur2) {
  int tid = threadIdx.x, b = blockIdx.x;
  int i = b * 256 + tid;
  int v = (i < NN) ? deg[i] : 0;
  int x = v;
#pragma unroll
  for (int d = 1; d < 64; d <<= 1) {
    int y = __shfl_up(x, d, 64);
    if ((tid & 63) >= d) x += y;
  }
  __shared__ int ws4[4];
  __shared__ int wo4[4];
  if ((tid & 63) == 63) ws4[tid >> 6] = x;
  __syncthreads();
  if (tid == 0) {
    int s = 0;
    for (int w2 = 0; w2 < 4; ++w2) { wo4[w2] = s; s += ws4[w2]; }
  }
  __syncthreads();
  int excl = x - v + wo4[tid >> 6] + bsum[b];
  if (i < NN) { row_ptr[i] = excl; cur2[i] = excl; }
  if (i == 0) row_ptr[NN] = EE;
}

// Kernel 3: scatter edge ids into relation-sorted perm (block-aggregated);
// DL: also emit dst-CSR value list (perm positions per dst).
template <bool DL>
__global__ __launch_bounds__(256) void k_scatter(const int* __restrict__ etype,
                                                 const int* __restrict__ dst,
                                                 int* __restrict__ cur,
                                                 int* __restrict__ perm,
                                                 int* __restrict__ cur2,
                                                 int* __restrict__ dlist) {
  __shared__ int lh[RR];
  __shared__ int lbase[RR];
  __shared__ int lcur[RR];
  int tid = threadIdx.x;
  int e0 = blockIdx.x * SCHUNK;
  for (int i = tid; i < RR; i += 256) lh[i] = 0;
  __syncthreads();
  for (int i = tid; i < SCHUNK; i += 256) {
    int e = e0 + i;
    if (e < EE) atomicAdd(&lh[etype[e]], 1);
  }
  __syncthreads();
  for (int i = tid; i < RR; i += 256) {
    int c = lh[i];
    lbase[i] = c ? atomicAdd(&cur[i], c) : 0;
    lcur[i] = 0;
  }
  __syncthreads();
  for (int i = tid; i < SCHUNK; i += 256) {
    int e = e0 + i;
    if (e < EE) {
      int et = etype[e];
      int s = lbase[et] + atomicAdd(&lcur[et], 1);
      perm[s] = e;
      if (DL) {
        int d = dst[e];
        int pos = atomicAdd(&cur2[d], 1);
        dlist[pos] = s;
      }
    }
  }
}

// ---------------------------------------------------------------------------
// Shared 64x256 @ 256x256 MFMA core. lA: 64 rows x 512B bf16 in LDS,
// byte ^= ((row&7)<<4) swizzle.
__device__ __forceinline__ void gemm64(const char* lA, const short* __restrict__ wpk,
                                       f32x4 acc[4][4], int wave, int lane) {
  int l15 = lane & 15, lg = lane >> 4;
  const short* bp = wpk + (size_t)wave * 4 * 4096 + (size_t)lane * 8;
#pragma unroll
  for (int kt = 0; kt < 8; ++kt) {
    short8v a[4], b[4];
#pragma unroll
    for (int c = 0; c < 4; ++c) b[c] = *(const short8v*)(bp + c * 4096 + kt * 512);
#pragma unroll
    for (int m = 0; m < 4; ++m) {
      int row = m * 16 + l15;
      int off = (row * 512 + kt * 64 + lg * 16) ^ ((row & 7) << 4);
      a[m] = *(const short8v*)(lA + off);
    }
#pragma unroll
    for (int m = 0; m < 4; ++m)
#pragma unroll
      for (int c = 0; c < 4; ++c)
        acc[m][c] = __builtin_amdgcn_mfma_f32_16x16x32_bf16(a[m], b[c], acc[m][c], 0, 0, 0);
  }
}

// ---------------------------------------------------------------------------
// Kernel 5 (tier A): pipelined edge GEMM. 4 tiles/block; next tile's metadata
// (per-wave, lanes 0-15 + shfl, no barriers) and 64-row feature gather issue
// before current tile's MFMA -> latency hidden. Writes scaled bf16 msg rows.
__global__ __launch_bounds__(256, 3) void k_edge_gemm_p(
    const unsigned short* __restrict__ featb, const short* __restrict__ wpk,
    const int* __restrict__ src, const int* __restrict__ dst,
    const int* __restrict__ deg, const int* __restrict__ perm,
    const int4* __restrict__ tdesc, unsigned short* __restrict__ msg) {
  __shared__ __align__(16) char lA[32768];
  __shared__ int   ldst2[2][64];
  __shared__ float linv2[2][64];
  int tid = threadIdx.x, wave = tid >> 6, lane = tid & 63;
  int l15 = lane & 15, lg = lane >> 4;
  int b = blockIdx.x;
  int t0 = ((b & 7) * EQ + (b >> 3)) * TPB;   // XCD-contiguous tile range

  short8v av[8];
  int rows_c, r_c, rs_c, sv_c;

#define META_(TILE, BUF, ROWS, RC, RSC, SVC) {                        \
    int4 dd4 = tdesc[TILE];                                           \
    ROWS = dd4.z; RC = dd4.x; RSC = dd4.y;                            \
    int sv_ = 0;                                                      \
    if (lane < 16 && ROWS > 0) {                                      \
      int row_ = (wave << 4) + lane;                                  \
      int e_ = perm[RSC + min(row_, ROWS - 1)];                       \
      sv_ = src[e_];                                                  \
      int dv_ = dst[e_];                                              \
      float li_ = 1.0f / (float)max(deg[dv_], 1);                     \
      ldst2[BUF][row_] = (row_ < ROWS) ? dv_ : -1;                    \
      linv2[BUF][row_] = (row_ < ROWS) ? li_ : 0.f;                   \
    }                                                                 \
    SVC = sv_;                                                        \
  }

#define GATHER_(SVC) {                                                \
    _Pragma("unroll")                                                 \
    for (int u = 0; u < 8; ++u) {                                     \
      int srow_ = __shfl(SVC, 2 * u + (lane >> 5), 64);               \
      av[u] = *(const short8v*)(featb + (size_t)srow_ * 256 + (lane & 31) * 8); \
    }                                                                 \
  }

  META_(t0, 0, rows_c, r_c, rs_c, sv_c);
  if (rows_c > 0) GATHER_(sv_c);

  for (int i = 0; i < TPB; ++i) {
    int cb = i & 1;
    if (rows_c > 0) {
#pragma unroll
      for (int u = 0; u < 8; ++u) {
        int row = (wave << 4) + 2 * u + (lane >> 5);
        *(short8v*)(lA + ((row * 512 + (lane & 31) * 16) ^ ((row & 7) << 4))) = av[u];
      }
    }
    __syncthreads();                        // (1) lA ready
    int rows_n = 0, r_n = 0, rs_n = 0, sv_n = 0;
    if (i + 1 < TPB) {
      META_(t0 + i + 1, cb ^ 1, rows_n, r_n, rs_n, sv_n);
      if (rows_n > 0) GATHER_(sv_n);        // loads in flight under MFMA
    }
    if (rows_c > 0) {
      f32x4 acc[4][4];
#pragma unroll
      for (int m = 0; m < 4; ++m)
#pragma unroll
        for (int c = 0; c < 4; ++c) acc[m][c] = (f32x4){0.f, 0.f, 0.f, 0.f};
      gemm64(lA, wpk + (size_t)r_c * 65536, acc, wave, lane);
      __syncthreads();                      // (2) done reading lA
      // scale + repack bf16 msg via lA
#pragma unroll
      for (int m = 0; m < 4; ++m)
#pragma unroll
        for (int j = 0; j < 4; ++j) {
          int row = m * 16 + lg * 4 + j;
          float inv = linv2[cb][row];
          int rb = row * 512, sw = (row & 7) << 4;
#pragma unroll
          for (int c = 0; c < 4; ++c) {
            int col = wave * 64 + c * 16 + l15;
            *(unsigned short*)(lA + ((rb + col * 2) ^ sw)) = f2bf(acc[m][c][j] * inv);
          }
        }
      __syncthreads();                      // (3) repack visible
#pragma unroll
      for (int u = 0; u < 8; ++u) {
        int idx = u * 256 + tid;
        int row = idx >> 5, q = idx & 31;
        if (row < rows_c) {
          short8v vv = *(const short8v*)(lA + ((row * 512 + q * 16) ^ ((row & 7) << 4)));
          *(short8v*)(msg + (size_t)(rs_c + row) * 256 + q * 8) = vv;
        }
      }
    } else {
      __syncthreads();
      __syncthreads();
    }
    __syncthreads();                        // (4) before next ds_write
    rows_c = rows_n; r_c = r_n; rs_c = rs_n; sv_c = sv_n;
  }
#undef META_
#undef GATHER_
}

// ---------------------------------------------------------------------------
// Kernel 6 (tier A): fused self-loop GEMM + dst-CSR aggregation.
// GEMM acc -> LDS f32 tile (stride 260 floats, conflict-free); waves sum msg
// rows into the tile; single coalesced write of out.
__global__ __launch_bounds__(256, 2) void k_self_agg(
    const unsigned short* __restrict__ featb, const short* __restrict__ spk,
    const unsigned short* __restrict__ msg, const int* __restrict__ row_ptr,
    const int* __restrict__ dlist, float* __restrict__ out) {
  __shared__ __align__(16) char uni[66560];  // max(32KB bf16 A, 64x260 f32)
  char* lA = uni;
  float* fT = (float*)uni;
  int tid = threadIdx.x, wave = tid >> 6, lane = tid & 63;
  int l15 = lane & 15, lg = lane >> 4;
  int n0 = blockIdx.x * 64;
  // stage A (contiguous rows, coalesced)
  short8v av[8];
#pragma unroll
  for (int u = 0; u < 8; ++u) {
    int idx = u * 256 + tid;
    int row = idx >> 5, q = idx & 31;
    int n = min(n0 + row, NN - 1);
    av[u] = *(const short8v*)(featb + (size_t)n * 256 + q * 8);
  }
#pragma unroll
  for (int u = 0; u < 8; ++u) {
    int idx = u * 256 + tid;
    int row = idx >> 5, q = idx & 31;
    *(short8v*)(lA + ((row * 512 + q * 16) ^ ((row & 7) << 4))) = av[u];
  }
  __syncthreads();
  f32x4 acc[4][4];
#pragma unroll
  for (int m = 0; m < 4; ++m)
#pragma unroll
    for (int c = 0; c < 4; ++c) acc[m][c] = (f32x4){0.f, 0.f, 0.f, 0.f};
  gemm64(lA, spk, acc, wave, lane);
  __syncthreads();                           // done with lA; reuse as f32 tile
#pragma unroll
  for (int m = 0; m < 4; ++m)
#pragma unroll
    for (int j = 0; j < 4; ++j) {
      int row = m * 16 + lg * 4 + j;
#pragma unroll
      for (int c = 0; c < 4; ++c)
        fT[row * 260 + wave * 64 + c * 16 + l15] = acc[m][c][j];
    }
  __syncthreads();
  // aggregate msg rows; wave w owns rows w*16..w*16+15
  for (int rr2 = 0; rr2 < 16; ++rr2) {
    int row = (wave << 4) + rr2;
    int n = n0 + row;
    if (n >= NN) break;
    int lo = row_ptr[n], hi = row_ptr[n + 1];
    if (lo >= hi) continue;
    float4 a = make_float4(0.f, 0.f, 0.f, 0.f);
    for (int q0 = lo; q0 < hi; q0 += 64) {
      int qm = min(64, hi - q0);
      int pv = (q0 + lane < hi) ? dlist[q0 + lane] : 0;
      for (int j = 0; j < qm; ++j) {
        int p = __shfl(pv, j, 64);
        ushort4 mv = *(const ushort4*)(msg + (size_t)p * 256 + lane * 4);
        a.x += bf2f(mv.x); a.y += bf2f(mv.y); a.z += bf2f(mv.z); a.w += bf2f(mv.w);
      }
    }
    float* fr = fT + row * 260 + lane * 4;
    fr[0] += a.x; fr[1] += a.y; fr[2] += a.z; fr[3] += a.w;
  }
  __syncthreads();
#pragma unroll
  for (int k2 = 0; k2 < 16; ++k2) {
    int idx = k2 * 256 + tid;
    int row = idx >> 6, q = idx & 63;
    int n = n0 + row;
    if (n < NN) {
      f32x4 v = *(const f32x4*)(fT + row * 260 + q * 4);
      *(f32x4*)(out + (size_t)n * 256 + q * 4) = v;
    }
  }
}

// ---------------------------------------------------------------------------
// Tier B/C fallbacks (atomic epilogue), as in round 2/3.
template <bool B16>
__global__ __launch_bounds__(256) void k_self_gemm(const float* __restrict__ in_feat,
                                                   const unsigned short* __restrict__ featb,
                                                   const short* __restrict__ spk,
                                                   float* __restrict__ out) {
  __shared__ __align__(16) char lA[32768];
  int n0 = blockIdx.x * 64;
  int tid = threadIdx.x;
  if (B16) {
    short8v sv[8];
#pragma unroll
    for (int u = 0; u < 8; ++u) {
      int idx = u * 256 + tid;
      int row = idx >> 5, q = idx & 31;
      int n = min(n0 + row, NN - 1);
      sv[u] = *(const short8v*)(featb + (size_t)n * 256 + q * 8);
    }
#pragma unroll
    for (int u = 0; u < 8; ++u) {
      int idx = u * 256 + tid;
      int row = idx >> 5, q = idx & 31;
      *(short8v*)(lA + ((row * 512 + q * 16) ^ ((row & 7) << 4))) = sv[u];
    }
  } else {
#pragma unroll
    for (int half = 0; half < 2; ++half) {
      float4 v[8];
#pragma unroll
      for (int u = 0; u < 8; ++u) {
        int it = half * 2048 + u * 256 + tid;
        int row = it >> 6, q = it & 63;
        int n = n0 + row;
        v[u] = (n < NN) ? ((const float4*)(in_feat + (size_t)n * 256))[q]
                        : make_float4(0.f, 0.f, 0.f, 0.f);
      }
#pragma unroll
      for (int u = 0; u < 8; ++u) {
        int it = half * 2048 + u * 256 + tid;
        int row = it >> 6, q = it & 63;
        ushort4 hh;
        hh.x = f2bf(v[u].x); hh.y = f2bf(v[u].y); hh.z = f2bf(v[u].z); hh.w = f2bf(v[u].w);
        *(ushort4*)(lA + ((row * 512 + q * 8) ^ ((row & 7) << 4))) = hh;
      }
    }
  }
  __syncthreads();
  f32x4 acc[4][4];
#pragma unroll
  for (int m = 0; m < 4; ++m)
#pragma unroll
    for (int c = 0; c < 4; ++c) acc[m][c] = (f32x4){0.f, 0.f, 0.f, 0.f};
  int wave = tid >> 6, lane = tid & 63;
  gemm64(lA, spk, acc, wave, lane);
  int l15 = lane & 15, lg = lane >> 4;
#pragma unroll
  for (int m = 0; m < 4; ++m)
#pragma unroll
    for (int j = 0; j < 4; ++j) {
      int n = n0 + m * 16 + lg * 4 + j;
      if (n < NN) {
        float* op = out + (size_t)n * 256 + wave * 64 + l15;
#pragma unroll
        for (int c = 0; c < 4; ++c) op[c * 16] = acc[m][c][j];
      }
    }
}

template <int MODE>   // 0: f32 feat, 1: bf16 feat; atomic mean-scatter
__global__ __launch_bounds__(256) void k_edge_gemm(const float* __restrict__ in_feat,
                                                   const unsigned short* __restrict__ featb,
                                                   const short* __restrict__ wpk,
                                                   const int* __restrict__ src,
                                                   const int* __restrict__ dst,
                                                   const int* __restrict__ deg,
                                                   const int* __restrict__ perm,
                                                   const int4* __restrict__ tdesc,
                                                   float* __restrict__ out) {
  __shared__ __align__(16) char lA[32768];
  __shared__ int lsrc[64];
  __shared__ int ldst[64];
  __shared__ float linv[64];
  int bid = blockIdx.x;
  int tile = (bid & 7) * (MAXTILES / 8) + (bid >> 3);
  int4 d = tdesc[tile];
  int rows = d.z;
  if (rows <= 0) return;
  int r = d.x, rs = d.y;
  int tid = threadIdx.x;
  if (tid < 64) {
    if (tid < rows) {
      int e = perm[rs + tid];
      lsrc[tid] = src[e];
      int dd = dst[e];
      ldst[tid] = dd;
      linv[tid] = 1.0f / (float)max(deg[dd], 1);
    } else {
      lsrc[tid] = -1; ldst[tid] = -1; linv[tid] = 0.f;
    }
  }
  __syncthreads();
  if (MODE == 1) {
    short8v sv[8];
#pragma unroll
    for (int u = 0; u < 8; ++u) {
      int idx = u * 256 + tid;
      int row = idx >> 5, q = idx & 31;
      int s = lsrc[row];
      sv[u] = (s >= 0) ? *(const short8v*)(featb + (size_t)s * 256 + q * 8)
                       : (short8v){0, 0, 0, 0, 0, 0, 0, 0};
    }
#pragma unroll
    for (int u = 0; u < 8; ++u) {
      int idx = u * 256 + tid;
      int row = idx >> 5, q = idx & 31;
      *(short8v*)(lA + ((row * 512 + q * 16) ^ ((row & 7) << 4))) = sv[u];
    }
  } else {
#pragma unroll
    for (int half = 0; half < 2; ++half) {
      float4 v[8];
#pragma unroll
      for (int u = 0; u < 8; ++u) {
        int it = half * 2048 + u * 256 + tid;
        int row = it >> 6, q = it & 63;
        int s = lsrc[row];
        v[u] = (s >= 0) ? ((const float4*)(in_feat + (size_t)s * 256))[q]
                        : make_float4(0.f, 0.f, 0.f, 0.f);
      }
#pragma unroll
      for (int u = 0; u < 8; ++u) {
        int it = half * 2048 + u * 256 + tid;
        int row = it >> 6, q = it & 63;
        ushort4 hh;
        hh.x = f2bf(v[u].x); hh.y = f2bf(v[u].y); hh.z = f2bf(v[u].z); hh.w = f2bf(v[u].w);
        *(ushort4*)(lA + ((row * 512 + q * 8) ^ ((row & 7) << 4))) = hh;
      }
    }
  }
  __syncthreads();
  f32x4 acc[4][4];
#pragma unroll
  for (int m = 0; m < 4; ++m)
#pragma unroll
    for (int c = 0; c < 4; ++c) acc[m][c] = (f32x4){0.f, 0.f, 0.f, 0.f};
  int wave = tid >> 6, lane = tid & 63;
  gemm64(lA, wpk + (size_t)r * 65536, acc, wave, lane);
  int l15 = lane & 15, lg = lane >> 4;
#pragma unroll
  for (int m = 0; m < 4; ++m)
#pragma unroll
    for (int j = 0; j < 4; ++j) {
      int row = m * 16 + lg * 4 + j;
      int dd = ldst[row];
      if (dd >= 0) {
        float inv = linv[row];
        float* op = out + (size_t)dd * 256 + wave * 64 + l15;
#pragma unroll
        for (int c = 0; c < 4; ++c) unsafeAtomicAdd(op + c * 16, acc[m][c][j] * inv);
      }
    }
}

// ---------------------------------------------------------------------------
extern "C" void kernel_launch(void* const* d_in, const int* in_sizes, int n_in,
                              void* d_out, int out_size, void* d_ws, size_t ws_size,
                              hipStream_t stream) {
  const float* in_feat = (const float*)d_in[0];
  const float* basis   = (const float*)d_in[1];
  const float* coef    = (const float*)d_in[2];
  const float* slw     = (const float*)d_in[3];
  const int*   src     = (const int*)d_in[4];
  const int*   dst     = (const int*)d_in[5];
  const int*   etype   = (const int*)d_in[6];
  float* out = (float*)d_out;

  char* base = (char*)d_ws;
  char* w = base;
  auto alloc = [&](size_t bytes) {
    char* p = w;
    w += (bytes + 255) & ~(size_t)255;
    return p;
  };
  // base group (tier C)
  short* wpk  = (short*)alloc((size_t)RR * 65536 * 2);   // 26.2 MB
  short* spk  = (short*)alloc(65536 * 2);
  int*   perm = (int*)alloc((size_t)EE * 4);
  int*   deg  = (int*)alloc((size_t)NN * 4);
  int*   hist = (int*)alloc(RR * 4);
  int*   cur  = (int*)alloc(RR * 4);
  int4*  tdesc = (int4*)alloc((size_t)MAXTILES * 16);
  int*   bsum = (int*)alloc(NSCAN * 4);
  // tier B adds bf16 feat
  unsigned short* featb = (unsigned short*)alloc((size_t)NN * 256 * 2);  // 51.2 MB
  size_t need_b = (size_t)(w - base);
  // tier A adds dst-CSR + msg buffer
  int* row_ptr = (int*)alloc((size_t)(NN + 1) * 4);
  int* cur2    = (int*)alloc((size_t)NN * 4);
  int* dlist   = (int*)alloc((size_t)EE * 4);
  unsigned short* msg = (unsigned short*)alloc((size_t)EE * 256 * 2);    // 204.8 MB
  size_t need_a = (size_t)(w - base);

  bool tierA = ws_size >= need_a;
  bool tierB = ws_size >= need_b;

  hipMemsetAsync(hist, 0, RR * 4, stream);
  hipMemsetAsync(deg, 0, (size_t)NN * 4, stream);

  k_wgen<<<800, 256, 0, stream>>>(basis, coef, wpk);
  k_slwpk<<<32, 256, 0, stream>>>(slw, spk);

  if (tierA) {
    k_hist_feat<true><<<512, 256, 0, stream>>>(etype, dst, in_feat, hist, deg, featb);
    k_scan<<<1, 256, 0, stream>>>(hist, cur, tdesc);
    k_dscan_a<<<NSCAN, 256, 0, stream>>>(deg, bsum);
    k_dscan_b<<<1, 256, 0, stream>>>(bsum);
    k_dscan_c<<<NSCAN, 256, 0, stream>>>(deg, bsum, row_ptr, cur2);
    k_scatter<true><<<(EE + SCHUNK - 1) / SCHUNK, 256, 0, stream>>>(etype, dst, cur,
                                                                    perm, cur2, dlist);
    k_edge_gemm_p<<<EGRID, 256, 0, stream>>>(featb, wpk, src, dst, deg, perm, tdesc, msg);
    k_self_agg<<<(NN + 63) / 64, 256, 0, stream>>>(featb, spk, msg, row_ptr, dlist, out);
  } else if (tierB) {
    k_hist_feat<true><<<512, 256, 0, stream>>>(etype, dst, in_feat, hist, deg, featb);
    k_scan<<<1, 256, 0, stream>>>(hist, cur, tdesc);
    k_scatter<false><<<(EE + SCHUNK - 1) / SCHUNK, 256, 0, stream>>>(etype, dst, cur,
                                                                     perm, nullptr, nullptr);
    k_self_gemm<true><<<(NN + 63) / 64, 256, 0, stream>>>(in_feat, featb, spk, out);
    k_edge_gemm<1><<<MAXTILES, 256, 0, stream>>>(in_feat, featb, wpk, src, dst, deg,
                                                 perm, tdesc, out);
  } else {
    k_hist_feat<false><<<512, 256, 0, stream>>>(etype, dst, in_feat, hist, deg, nullptr);
    k_scan<<<1, 256, 0, stream>>>(hist, cur, tdesc);
    k_scatter<false><<<(EE + SCHUNK - 1) / SCHUNK, 256, 0, stream>>>(etype, dst, cur,
                                                                     perm, nullptr, nullptr);
    k_self_gemm<false><<<(NN + 63) / 64, 256, 0, stream>>>(in_feat, nullptr, spk, out);
    k_edge_gemm<0><<<MAXTILES, 256, 0, stream>>>(in_feat, nullptr, wpk, src, dst, deg,
                                                 perm, tdesc, out);
  }
}

// Round 5
// 401.300 us; speedup vs baseline: 1.9084x; 1.9084x over previous
//
#include <hip/hip_runtime.h>
#include <hip/hip_bf16.h>

// RGCN forward, MI355X. N=100000, E=400000, IN=OUT=256, R=200, B=32.
// Tier A: wgen (L2-blocked) -> hist+feat -> scan -> deg-scan -> scatter(+dlist)
//  -> col-split per-relation tile GEMMs (2 blocks per 64-edge tile, 64x128
//  output each, acc[4][2] keeps regs ~142 -> 3 waves/SIMD) writing scaled bf16
//  msg -> fused self-loop GEMM + group-parallel dst-CSR aggregation.
// Tiers B/C: atomic fallbacks.

#define NN 100000
#define EE 400000
#define RR 200
#define BB 32
#define MAXTILES 6464   // >= E/64 + R ; divisible by 32
#define EQ2 (MAXTILES * 2 / 8)   // 1616 ords per XCD
#define SCHUNK 2048
#define NSCAN ((NN + 255) / 256) // 391

typedef __attribute__((ext_vector_type(8))) short short8v;   // 8 x bf16 (16B)
typedef __attribute__((ext_vector_type(4))) float f32x4;

__device__ __forceinline__ unsigned short f2bf(float f) {
  unsigned u = __float_as_uint(f);
  u += 0x7FFF + ((u >> 16) & 1);          // RNE
  return (unsigned short)(u >> 16);
}
__device__ __forceinline__ float bf2f(unsigned short h) {
  return __uint_as_float(((unsigned)h) << 16);
}

// ---------------------------------------------------------------------------
// Kernel 0: W_pk[r] = bf16(coef[r] @ basis), packed for MFMA B-fragments.
// Layout per relation: [ct=16][kt=8][lane=64][j=8] bf16, where
//   value = W_r[k = kt*32 + (lane>>4)*8 + j][n = ct*16 + (lane&15)].
// Block mapping: XCD x gets ord [x*100,(x+1)*100) -> basis slice read once
// from HBM, reused from L2.
__global__ __launch_bounds__(256) void k_wgen(const float* __restrict__ basis,
                                              const float* __restrict__ coef,
                                              short* __restrict__ wpk) {
  int b = blockIdx.x;                      // 800 blocks
  int ord = (b & 7) * 100 + (b >> 3);
  int rg = ord % 25;
  int pk8 = (ord / 25) * 256 + threadIdx.x;
  int lane = pk8 & 63;
  int kt = (pk8 >> 6) & 7;
  int ct = pk8 >> 9;
  int n  = ct * 16 + (lane & 15);
  int k0 = kt * 32 + ((lane >> 4) << 3);
  float acc[8][8];
#pragma unroll
  for (int r = 0; r < 8; ++r)
#pragma unroll
    for (int j = 0; j < 8; ++j) acc[r][j] = 0.f;
  for (int bb = 0; bb < BB; ++bb) {
    float bas[8];
#pragma unroll
    for (int j = 0; j < 8; ++j) bas[j] = basis[bb * 65536 + (k0 + j) * 256 + n];
#pragma unroll
    for (int r = 0; r < 8; ++r) {
      float c = coef[(rg * 8 + r) * BB + bb];
#pragma unroll
      for (int j = 0; j < 8; ++j) acc[r][j] += c * bas[j];
    }
  }
#pragma unroll
  for (int r = 0; r < 8; ++r) {
    short8v v;
#pragma unroll
    for (int j = 0; j < 8; ++j) v[j] = (short)f2bf(acc[r][j]);
    *(short8v*)(wpk + (size_t)(rg * 8 + r) * 65536 + (size_t)pk8 * 8) = v;
  }
}

// Kernel 0b: pack self_loop_weight [256][256] f32 into same MFMA layout.
__global__ __launch_bounds__(256) void k_slwpk(const float* __restrict__ slw,
                                               short* __restrict__ spk) {
  int t = blockIdx.x * 256 + threadIdx.x;
  int lane = t & 63;
  int kt = (t >> 6) & 7;
  int ct = t >> 9;
  int n  = ct * 16 + (lane & 15);
  int k0 = kt * 32 + ((lane >> 4) << 3);
  short8v v;
#pragma unroll
  for (int j = 0; j < 8; ++j) v[j] = (short)f2bf(slw[(k0 + j) * 256 + n]);
  *(short8v*)(spk + (size_t)t * 8) = v;
}

// Kernel 1: etype histogram (LDS) + dst in-degree + (FEAT) f32->bf16 convert.
template <bool FEAT>
__global__ __launch_bounds__(256) void k_hist_feat(const int* __restrict__ etype,
                                                   const int* __restrict__ dst,
                                                   const float* __restrict__ in_feat,
                                                   int* __restrict__ hist,
                                                   int* __restrict__ deg,
                                                   unsigned short* __restrict__ featb) {
  __shared__ int lh[RR];
  int tid = threadIdx.x;
  for (int i = tid; i < RR; i += 256) lh[i] = 0;
  __syncthreads();
  for (int e = blockIdx.x * 256 + tid; e < EE; e += gridDim.x * 256) {
    atomicAdd(&lh[etype[e]], 1);
    atomicAdd(&deg[dst[e]], 1);
  }
  if (FEAT) {
    const int total = NN * 64;               // float4 count
    for (int i = blockIdx.x * 256 + tid; i < total; i += gridDim.x * 256) {
      float4 v = ((const float4*)in_feat)[i];
      ushort4 h;
      h.x = f2bf(v.x); h.y = f2bf(v.y); h.z = f2bf(v.z); h.w = f2bf(v.w);
      ((ushort4*)featb)[i] = h;
    }
  }
  __syncthreads();
  for (int i = tid; i < RR; i += 256)
    if (lh[i]) atomicAdd(&hist[i], lh[i]);
}

// Kernel 2 (single block): scan 200 etype bins, emit tile descs, init cursors.
__global__ __launch_bounds__(256) void k_scan(const int* __restrict__ hist,
                                              int* __restrict__ cur,
                                              int4* __restrict__ tdesc) {
  __shared__ int h[RR];
  __shared__ int off[RR];
  __shared__ int toff[RR];
  __shared__ int tot;
  int tid = threadIdx.x;
  for (int i = tid; i < RR; i += 256) h[i] = hist[i];
  __syncthreads();
  if (tid == 0) {
    int s = 0, ts = 0;
    for (int r = 0; r < RR; ++r) {
      off[r] = s; s += h[r];
      toff[r] = ts; ts += (h[r] + 63) >> 6;
    }
    tot = ts;
  }
  __syncthreads();
  if (tid < RR) {
    int r = tid, cnt = h[r], base = off[r], to = toff[r];
    cur[r] = base;
    int nt = (cnt + 63) >> 6;
    for (int t2 = 0; t2 < nt; ++t2)
      tdesc[to + t2] = make_int4(r, base + t2 * 64, min(64, cnt - t2 * 64), 0);
  }
  for (int i = tot + tid; i < MAXTILES; i += 256)
    tdesc[i] = make_int4(0, 0, 0, 0);
}

// --------- dst-CSR build: exclusive scan of deg ----------
__global__ __launch_bounds__(256) void k_dscan_a(const int* __restrict__ deg,
                                                 int* __restrict__ bsum) {
  int i = blockIdx.x * 256 + threadIdx.x;
  int v = (i < NN) ? deg[i] : 0;
#pragma unroll
  for (int d = 32; d; d >>= 1) v += __shfl_down(v, d, 64);
  __shared__ int ws4[4];
  if ((threadIdx.x & 63) == 0) ws4[threadIdx.x >> 6] = v;
  __syncthreads();
  if (threadIdx.x == 0) bsum[blockIdx.x] = ws4[0] + ws4[1] + ws4[2] + ws4[3];
}

__global__ __launch_bounds__(256) void k_dscan_b(int* __restrict__ bsum) {
  __shared__ int l[NSCAN];
  int tid = threadIdx.x;
  for (int i = tid; i < NSCAN; i += 256) l[i] = bsum[i];
  __syncthreads();
  if (tid == 0) {
    int s = 0;
    for (int i = 0; i < NSCAN; ++i) { int t = l[i]; l[i] = s; s += t; }
  }
  __syncthreads();
  for (int i = tid; i < NSCAN; i += 256) bsum[i] = l[i];
}

__global__ __launch_bounds__(256) void k_dscan_c(const int* __restrict__ deg,
                                                 const int* __restrict__ bsum,
                                                 int* __restrict__ row_ptr,
                                                 int* __restrict__ cur2) {
  int tid = threadIdx.x, b = blockIdx.x;
  int i = b * 256 + tid;
  int v = (i < NN) ? deg[i] : 0;
  int x = v;
#pragma unroll
  for (int d = 1; d < 64; d <<= 1) {
    int y = __shfl_up(x, d, 64);
    if ((tid & 63) >= d) x += y;
  }
  __shared__ int ws4[4];
  __shared__ int wo4[4];
  if ((tid & 63) == 63) ws4[tid >> 6] = x;
  __syncthreads();
  if (tid == 0) {
    int s = 0;
    for (int w2 = 0; w2 < 4; ++w2) { wo4[w2] = s; s += ws4[w2]; }
  }
  __syncthreads();
  int excl = x - v + wo4[tid >> 6] + bsum[b];
  if (i < NN) { row_ptr[i] = excl; cur2[i] = excl; }
  if (i == 0) row_ptr[NN] = EE;
}

// Kernel 3: scatter edge ids into relation-sorted perm (block-aggregated);
// DL: also emit dst-CSR value list (perm positions per dst).
template <bool DL>
__global__ __launch_bounds__(256) void k_scatter(const int* __restrict__ etype,
                                                 const int* __restrict__ dst,
                                                 int* __restrict__ cur,
                                                 int* __restrict__ perm,
                                                 int* __restrict__ cur2,
                                                 int* __restrict__ dlist) {
  __shared__ int lh[RR];
  __shared__ int lbase[RR];
  __shared__ int lcur[RR];
  int tid = threadIdx.x;
  int e0 = blockIdx.x * SCHUNK;
  for (int i = tid; i < RR; i += 256) lh[i] = 0;
  __syncthreads();
  for (int i = tid; i < SCHUNK; i += 256) {
    int e = e0 + i;
    if (e < EE) atomicAdd(&lh[etype[e]], 1);
  }
  __syncthreads();
  for (int i = tid; i < RR; i += 256) {
    int c = lh[i];
    lbase[i] = c ? atomicAdd(&cur[i], c) : 0;
    lcur[i] = 0;
  }
  __syncthreads();
  for (int i = tid; i < SCHUNK; i += 256) {
    int e = e0 + i;
    if (e < EE) {
      int et = etype[e];
      int s = lbase[et] + atomicAdd(&lcur[et], 1);
      perm[s] = e;
      if (DL) {
        int d = dst[e];
        int pos = atomicAdd(&cur2[d], 1);
        dlist[pos] = s;
      }
    }
  }
}

// ---------------------------------------------------------------------------
// Kernel 5 (tier A): col-split edge GEMM. 2 blocks per 64-edge tile; block
// computes 64 rows x 128 cols -> acc[4][2] (32 AGPR) keeps unified reg count
// ~142 -> 3 waves/SIMD. B fragments prefetched one kt ahead. Writes scaled
// bf16 msg rows (no atomics).
__global__ __launch_bounds__(256) void k_edge_gemm5(
    const unsigned short* __restrict__ featb, const short* __restrict__ wpk,
    const int* __restrict__ src, const int* __restrict__ dst,
    const int* __restrict__ deg, const int* __restrict__ perm,
    const int4* __restrict__ tdesc, unsigned short* __restrict__ msg) {
  __shared__ __align__(16) char lA[32768];
  __shared__ int lsrc[64];
  __shared__ float linv[64];
  int tid = threadIdx.x, wave = tid >> 6, lane = tid & 63;
  int l15 = lane & 15, lg = lane >> 4;
  // XCD x processes ords [x*1616,(x+1)*1616) = tiles [x*808,(x+1)*808) x 2 halves
  int bid = blockIdx.x;
  int ord = (bid & 7) * EQ2 + (bid >> 3);
  int tile = ord >> 1, half = ord & 1;
  int4 d = tdesc[tile];
  int rows = d.z;
  if (rows <= 0) return;
  int r = d.x, rs = d.y;
  if (tid < 64) {
    if (tid < rows) {
      int e = perm[rs + tid];
      lsrc[tid] = src[e];
      linv[tid] = 1.0f / (float)max(deg[dst[e]], 1);
    } else {
      lsrc[tid] = -1; linv[tid] = 0.f;
    }
  }
  __syncthreads();
  // stage full 64x256 A tile (K unsplit), swizzled
  short8v sv[8];
#pragma unroll
  for (int u = 0; u < 8; ++u) {
    int idx = u * 256 + tid;
    int row = idx >> 5, q = idx & 31;
    int s = lsrc[row];
    sv[u] = (s >= 0) ? *(const short8v*)(featb + (size_t)s * 256 + q * 8)
                     : (short8v){0, 0, 0, 0, 0, 0, 0, 0};
  }
#pragma unroll
  for (int u = 0; u < 8; ++u) {
    int idx = u * 256 + tid;
    int row = idx >> 5, q = idx & 31;
    *(short8v*)(lA + ((row * 512 + q * 16) ^ ((row & 7) << 4))) = sv[u];
  }
  __syncthreads();
  f32x4 acc[4][2];
#pragma unroll
  for (int m = 0; m < 4; ++m)
#pragma unroll
    for (int c = 0; c < 2; ++c) acc[m][c] = (f32x4){0.f, 0.f, 0.f, 0.f};
  // B: this block's ct range = half*8 + wave*2 + {0,1}
  const short* bp = wpk + (size_t)r * 65536 +
                    (size_t)(half * 8 + wave * 2) * 4096 + (size_t)lane * 8;
  short8v b0 = *(const short8v*)(bp);
  short8v b1 = *(const short8v*)(bp + 4096);
#pragma unroll
  for (int kt = 0; kt < 8; ++kt) {
    short8v bn0, bn1;
    if (kt < 7) {
      bn0 = *(const short8v*)(bp + (kt + 1) * 512);
      bn1 = *(const short8v*)(bp + 4096 + (kt + 1) * 512);
    }
    short8v a[4];
#pragma unroll
    for (int m = 0; m < 4; ++m) {
      int row = m * 16 + l15;
      a[m] = *(const short8v*)(lA + ((row * 512 + kt * 64 + lg * 16) ^ ((row & 7) << 4)));
    }
#pragma unroll
    for (int m = 0; m < 4; ++m) {
      acc[m][0] = __builtin_amdgcn_mfma_f32_16x16x32_bf16(a[m], b0, acc[m][0], 0, 0, 0);
      acc[m][1] = __builtin_amdgcn_mfma_f32_16x16x32_bf16(a[m], b1, acc[m][1], 0, 0, 0);
    }
    if (kt < 7) { b0 = bn0; b1 = bn1; }
  }
  __syncthreads();                            // done reading lA
  // scale + repack bf16 (cols local [0,128)) via lA, then coalesced store
#pragma unroll
  for (int m = 0; m < 4; ++m)
#pragma unroll
    for (int j = 0; j < 4; ++j) {
      int row = m * 16 + lg * 4 + j;
      float inv = linv[row];
      int rb = row * 512, sw = (row & 7) << 4;
#pragma unroll
      for (int c = 0; c < 2; ++c) {
        int col = wave * 32 + c * 16 + l15;
        *(unsigned short*)(lA + ((rb + col * 2) ^ sw)) = f2bf(acc[m][c][j] * inv);
      }
    }
  __syncthreads();
#pragma unroll
  for (int u = 0; u < 4; ++u) {
    int idx = u * 256 + tid;
    int row = idx >> 4, q = idx & 15;         // 64 rows x 16 chunks of 16B
    if (row < rows) {
      short8v vv = *(const short8v*)(lA + ((row * 512 + q * 16) ^ ((row & 7) << 4)));
      *(short8v*)(msg + (size_t)(rs + row) * 256 + half * 128 + q * 8) = vv;
    }
  }
}

// ---------------------------------------------------------------------------
// Kernel 6 (tier A): fused self-loop GEMM + dst-CSR aggregation.
// GEMM acc -> LDS f32 tile (stride 260); 16-lane groups aggregate msg rows
// (4 rows in flight per wave, 512B coalesced per msg row); single write of out.
__global__ __launch_bounds__(256) void k_self_agg(
    const unsigned short* __restrict__ featb, const short* __restrict__ spk,
    const unsigned short* __restrict__ msg, const int* __restrict__ row_ptr,
    const int* __restrict__ dlist, float* __restrict__ out) {
  __shared__ __align__(16) char uni[66560];  // max(32KB bf16 A, 64x260 f32)
  char* lA = uni;
  float* fT = (float*)uni;
  int tid = threadIdx.x, wave = tid >> 6, lane = tid & 63;
  int l15 = lane & 15, lg = lane >> 4;
  int n0 = blockIdx.x * 64;
  // stage A (contiguous rows, coalesced)
  short8v av[8];
#pragma unroll
  for (int u = 0; u < 8; ++u) {
    int idx = u * 256 + tid;
    int row = idx >> 5, q = idx & 31;
    int n = min(n0 + row, NN - 1);
    av[u] = *(const short8v*)(featb + (size_t)n * 256 + q * 8);
  }
#pragma unroll
  for (int u = 0; u < 8; ++u) {
    int idx = u * 256 + tid;
    int row = idx >> 5, q = idx & 31;
    *(short8v*)(lA + ((row * 512 + q * 16) ^ ((row & 7) << 4))) = av[u];
  }
  __syncthreads();
  f32x4 acc[4][4];
#pragma unroll
  for (int m = 0; m < 4; ++m)
#pragma unroll
    for (int c = 0; c < 4; ++c) acc[m][c] = (f32x4){0.f, 0.f, 0.f, 0.f};
  {
    const short* bp = spk + (size_t)wave * 4 * 4096 + (size_t)lane * 8;
#pragma unroll
    for (int kt = 0; kt < 8; ++kt) {
      short8v a[4], b[4];
#pragma unroll
      for (int c = 0; c < 4; ++c) b[c] = *(const short8v*)(bp + c * 4096 + kt * 512);
#pragma unroll
      for (int m = 0; m < 4; ++m) {
        int row = m * 16 + l15;
        a[m] = *(const short8v*)(lA + ((row * 512 + kt * 64 + lg * 16) ^ ((row & 7) << 4)));
      }
#pragma unroll
      for (int m = 0; m < 4; ++m)
#pragma unroll
        for (int c = 0; c < 4; ++c)
          acc[m][c] = __builtin_amdgcn_mfma_f32_16x16x32_bf16(a[m], b[c], acc[m][c], 0, 0, 0);
    }
  }
  __syncthreads();                           // done with lA; reuse as f32 tile
#pragma unroll
  for (int m = 0; m < 4; ++m)
#pragma unroll
    for (int j = 0; j < 4; ++j) {
      int row = m * 16 + lg * 4 + j;
#pragma unroll
      for (int c = 0; c < 4; ++c)
        fT[row * 260 + wave * 64 + c * 16 + l15] = acc[m][c][j];
    }
  __syncthreads();
  // aggregate: 16-lane groups; group handles one dst row (lane = 16 cols);
  // 4 rows in flight per wave.
  int grp = lane >> 4, gl = lane & 15;
  for (int rr = 0; rr < 4; ++rr) {
    int row = (wave << 4) + (rr << 2) + grp;
    int n = n0 + row;
    int lo = 0, hi = 0;
    if (n < NN) { lo = row_ptr[n]; hi = row_ptr[n + 1]; }
    if (lo >= hi) continue;
    float a[16];
#pragma unroll
    for (int k = 0; k < 16; ++k) a[k] = 0.f;
    for (int q0 = lo; q0 < hi; q0 += 16) {
      int pv = (q0 + gl < hi) ? dlist[q0 + gl] : 0;
      int qm = min(16, hi - q0);
      for (int j = 0; j < qm; ++j) {
        int p = __shfl(pv, (grp << 4) + j, 64);
        const unsigned short* mp = msg + (size_t)p * 256 + gl * 16;
        short8v m0 = *(const short8v*)mp;
        short8v m1 = *(const short8v*)(mp + 8);
#pragma unroll
        for (int k = 0; k < 8; ++k) {
          a[k]     += bf2f((unsigned short)m0[k]);
          a[k + 8] += bf2f((unsigned short)m1[k]);
        }
      }
    }
    float* fr = fT + row * 260 + gl * 16;
#pragma unroll
    for (int k = 0; k < 16; ++k) fr[k] += a[k];
  }
  __syncthreads();
#pragma unroll
  for (int k2 = 0; k2 < 16; ++k2) {
    int idx = k2 * 256 + tid;
    int row = idx >> 6, q = idx & 63;
    int n = n0 + row;
    if (n < NN) {
      f32x4 v = *(const f32x4*)(fT + row * 260 + q * 4);
      *(f32x4*)(out + (size_t)n * 256 + q * 4) = v;
    }
  }
}

// ---------------------------------------------------------------------------
// Tier B/C fallbacks (atomic epilogue).
__device__ __forceinline__ void gemm64(const char* lA, const short* __restrict__ wpk,
                                       f32x4 acc[4][4], int wave, int lane) {
  int l15 = lane & 15, lg = lane >> 4;
  const short* bp = wpk + (size_t)wave * 4 * 4096 + (size_t)lane * 8;
#pragma unroll
  for (int kt = 0; kt < 8; ++kt) {
    short8v a[4], b[4];
#pragma unroll
    for (int c = 0; c < 4; ++c) b[c] = *(const short8v*)(bp + c * 4096 + kt * 512);
#pragma unroll
    for (int m = 0; m < 4; ++m) {
      int row = m * 16 + l15;
      a[m] = *(const short8v*)(lA + ((row * 512 + kt * 64 + lg * 16) ^ ((row & 7) << 4)));
    }
#pragma unroll
    for (int m = 0; m < 4; ++m)
#pragma unroll
      for (int c = 0; c < 4; ++c)
        acc[m][c] = __builtin_amdgcn_mfma_f32_16x16x32_bf16(a[m], b[c], acc[m][c], 0, 0, 0);
  }
}

template <bool B16>
__global__ __launch_bounds__(256) void k_self_gemm(const float* __restrict__ in_feat,
                                                   const unsigned short* __restrict__ featb,
                                                   const short* __restrict__ spk,
                                                   float* __restrict__ out) {
  __shared__ __align__(16) char lA[32768];
  int n0 = blockIdx.x * 64;
  int tid = threadIdx.x;
  if (B16) {
    short8v sv[8];
#pragma unroll
    for (int u = 0; u < 8; ++u) {
      int idx = u * 256 + tid;
      int row = idx >> 5, q = idx & 31;
      int n = min(n0 + row, NN - 1);
      sv[u] = *(const short8v*)(featb + (size_t)n * 256 + q * 8);
    }
#pragma unroll
    for (int u = 0; u < 8; ++u) {
      int idx = u * 256 + tid;
      int row = idx >> 5, q = idx & 31;
      *(short8v*)(lA + ((row * 512 + q * 16) ^ ((row & 7) << 4))) = sv[u];
    }
  } else {
#pragma unroll
    for (int half = 0; half < 2; ++half) {
      float4 v[8];
#pragma unroll
      for (int u = 0; u < 8; ++u) {
        int it = half * 2048 + u * 256 + tid;
        int row = it >> 6, q = it & 63;
        int n = n0 + row;
        v[u] = (n < NN) ? ((const float4*)(in_feat + (size_t)n * 256))[q]
                        : make_float4(0.f, 0.f, 0.f, 0.f);
      }
#pragma unroll
      for (int u = 0; u < 8; ++u) {
        int it = half * 2048 + u * 256 + tid;
        int row = it >> 6, q = it & 63;
        ushort4 hh;
        hh.x = f2bf(v[u].x); hh.y = f2bf(v[u].y); hh.z = f2bf(v[u].z); hh.w = f2bf(v[u].w);
        *(ushort4*)(lA + ((row * 512 + q * 8) ^ ((row & 7) << 4))) = hh;
      }
    }
  }
  __syncthreads();
  f32x4 acc[4][4];
#pragma unroll
  for (int m = 0; m < 4; ++m)
#pragma unroll
    for (int c = 0; c < 4; ++c) acc[m][c] = (f32x4){0.f, 0.f, 0.f, 0.f};
  int wave = tid >> 6, lane = tid & 63;
  gemm64(lA, spk, acc, wave, lane);
  int l15 = lane & 15, lg = lane >> 4;
#pragma unroll
  for (int m = 0; m < 4; ++m)
#pragma unroll
    for (int j = 0; j < 4; ++j) {
      int n = n0 + m * 16 + lg * 4 + j;
      if (n < NN) {
        float* op = out + (size_t)n * 256 + wave * 64 + l15;
#pragma unroll
        for (int c = 0; c < 4; ++c) op[c * 16] = acc[m][c][j];
      }
    }
}

template <int MODE>   // 0: f32 feat, 1: bf16 feat; atomic mean-scatter
__global__ __launch_bounds__(256) void k_edge_gemm(const float* __restrict__ in_feat,
                                                   const unsigned short* __restrict__ featb,
                                                   const short* __restrict__ wpk,
                                                   const int* __restrict__ src,
                                                   const int* __restrict__ dst,
                                                   const int* __restrict__ deg,
                                                   const int* __restrict__ perm,
                                                   const int4* __restrict__ tdesc,
                                                   float* __restrict__ out) {
  __shared__ __align__(16) char lA[32768];
  __shared__ int lsrc[64];
  __shared__ int ldst[64];
  __shared__ float linv[64];
  int bid = blockIdx.x;
  int tile = (bid & 7) * (MAXTILES / 8) + (bid >> 3);
  int4 d = tdesc[tile];
  int rows = d.z;
  if (rows <= 0) return;
  int r = d.x, rs = d.y;
  int tid = threadIdx.x;
  if (tid < 64) {
    if (tid < rows) {
      int e = perm[rs + tid];
      lsrc[tid] = src[e];
      int dd = dst[e];
      ldst[tid] = dd;
      linv[tid] = 1.0f / (float)max(deg[dd], 1);
    } else {
      lsrc[tid] = -1; ldst[tid] = -1; linv[tid] = 0.f;
    }
  }
  __syncthreads();
  if (MODE == 1) {
    short8v sv[8];
#pragma unroll
    for (int u = 0; u < 8; ++u) {
      int idx = u * 256 + tid;
      int row = idx >> 5, q = idx & 31;
      int s = lsrc[row];
      sv[u] = (s >= 0) ? *(const short8v*)(featb + (size_t)s * 256 + q * 8)
                       : (short8v){0, 0, 0, 0, 0, 0, 0, 0};
    }
#pragma unroll
    for (int u = 0; u < 8; ++u) {
      int idx = u * 256 + tid;
      int row = idx >> 5, q = idx & 31;
      *(short8v*)(lA + ((row * 512 + q * 16) ^ ((row & 7) << 4))) = sv[u];
    }
  } else {
#pragma unroll
    for (int half = 0; half < 2; ++half) {
      float4 v[8];
#pragma unroll
      for (int u = 0; u < 8; ++u) {
        int it = half * 2048 + u * 256 + tid;
        int row = it >> 6, q = it & 63;
        int s = lsrc[row];
        v[u] = (s >= 0) ? ((const float4*)(in_feat + (size_t)s * 256))[q]
                        : make_float4(0.f, 0.f, 0.f, 0.f);
      }
#pragma unroll
      for (int u = 0; u < 8; ++u) {
        int it = half * 2048 + u * 256 + tid;
        int row = it >> 6, q = it & 63;
        ushort4 hh;
        hh.x = f2bf(v[u].x); hh.y = f2bf(v[u].y); hh.z = f2bf(v[u].z); hh.w = f2bf(v[u].w);
        *(ushort4*)(lA + ((row * 512 + q * 8) ^ ((row & 7) << 4))) = hh;
      }
    }
  }
  __syncthreads();
  f32x4 acc[4][4];
#pragma unroll
  for (int m = 0; m < 4; ++m)
#pragma unroll
    for (int c = 0; c < 4; ++c) acc[m][c] = (f32x4){0.f, 0.f, 0.f, 0.f};
  int wave = tid >> 6, lane = tid & 63;
  gemm64(lA, wpk + (size_t)r * 65536, acc, wave, lane);
  int l15 = lane & 15, lg = lane >> 4;
#pragma unroll
  for (int m = 0; m < 4; ++m)
#pragma unroll
    for (int j = 0; j < 4; ++j) {
      int row = m * 16 + lg * 4 + j;
      int dd = ldst[row];
      if (dd >= 0) {
        float inv = linv[row];
        float* op = out + (size_t)dd * 256 + wave * 64 + l15;
#pragma unroll
        for (int c = 0; c < 4; ++c) unsafeAtomicAdd(op + c * 16, acc[m][c][j] * inv);
      }
    }
}

// ---------------------------------------------------------------------------
extern "C" void kernel_launch(void* const* d_in, const int* in_sizes, int n_in,
                              void* d_out, int out_size, void* d_ws, size_t ws_size,
                              hipStream_t stream) {
  const float* in_feat = (const float*)d_in[0];
  const float* basis   = (const float*)d_in[1];
  const float* coef    = (const float*)d_in[2];
  const float* slw     = (const float*)d_in[3];
  const int*   src     = (const int*)d_in[4];
  const int*   dst     = (const int*)d_in[5];
  const int*   etype   = (const int*)d_in[6];
  float* out = (float*)d_out;

  char* base = (char*)d_ws;
  char* w = base;
  auto alloc = [&](size_t bytes) {
    char* p = w;
    w += (bytes + 255) & ~(size_t)255;
    return p;
  };
  // base group (tier C)
  short* wpk  = (short*)alloc((size_t)RR * 65536 * 2);   // 26.2 MB
  short* spk  = (short*)alloc(65536 * 2);
  int*   perm = (int*)alloc((size_t)EE * 4);
  int*   deg  = (int*)alloc((size_t)NN * 4);
  int*   hist = (int*)alloc(RR * 4);
  int*   cur  = (int*)alloc(RR * 4);
  int4*  tdesc = (int4*)alloc((size_t)MAXTILES * 16);
  int*   bsum = (int*)alloc(NSCAN * 4);
  // tier B adds bf16 feat
  unsigned short* featb = (unsigned short*)alloc((size_t)NN * 256 * 2);  // 51.2 MB
  size_t need_b = (size_t)(w - base);
  // tier A adds dst-CSR + msg buffer
  int* row_ptr = (int*)alloc((size_t)(NN + 1) * 4);
  int* cur2    = (int*)alloc((size_t)NN * 4);
  int* dlist   = (int*)alloc((size_t)EE * 4);
  unsigned short* msg = (unsigned short*)alloc((size_t)EE * 256 * 2);    // 204.8 MB
  size_t need_a = (size_t)(w - base);

  bool tierA = ws_size >= need_a;
  bool tierB = ws_size >= need_b;

  hipMemsetAsync(hist, 0, RR * 4, stream);
  hipMemsetAsync(deg, 0, (size_t)NN * 4, stream);

  k_wgen<<<800, 256, 0, stream>>>(basis, coef, wpk);
  k_slwpk<<<32, 256, 0, stream>>>(slw, spk);

  if (tierA) {
    k_hist_feat<true><<<512, 256, 0, stream>>>(etype, dst, in_feat, hist, deg, featb);
    k_scan<<<1, 256, 0, stream>>>(hist, cur, tdesc);
    k_dscan_a<<<NSCAN, 256, 0, stream>>>(deg, bsum);
    k_dscan_b<<<1, 256, 0, stream>>>(bsum);
    k_dscan_c<<<NSCAN, 256, 0, stream>>>(deg, bsum, row_ptr, cur2);
    k_scatter<true><<<(EE + SCHUNK - 1) / SCHUNK, 256, 0, stream>>>(etype, dst, cur,
                                                                    perm, cur2, dlist);
    k_edge_gemm5<<<MAXTILES * 2, 256, 0, stream>>>(featb, wpk, src, dst, deg,
                                                   perm, tdesc, msg);
    k_self_agg<<<(NN + 63) / 64, 256, 0, stream>>>(featb, spk, msg, row_ptr, dlist, out);
  } else if (tierB) {
    k_hist_feat<true><<<512, 256, 0, stream>>>(etype, dst, in_feat, hist, deg, featb);
    k_scan<<<1, 256, 0, stream>>>(hist, cur, tdesc);
    k_scatter<false><<<(EE + SCHUNK - 1) / SCHUNK, 256, 0, stream>>>(etype, dst, cur,
                                                                     perm, nullptr, nullptr);
    k_self_gemm<true><<<(NN + 63) / 64, 256, 0, stream>>>(in_feat, featb, spk, out);
    k_edge_gemm<1><<<MAXTILES, 256, 0, stream>>>(in_feat, featb, wpk, src, dst, deg,
                                                 perm, tdesc, out);
  } else {
    k_hist_feat<false><<<512, 256, 0, stream>>>(etype, dst, in_feat, hist, deg, nullptr);
    k_scan<<<1, 256, 0, stream>>>(hist, cur, tdesc);
    k_scatter<false><<<(EE + SCHUNK - 1) / SCHUNK, 256, 0, stream>>>(etype, dst, cur,
                                                                     perm, nullptr, nullptr);
    k_self_gemm<false><<<(NN + 63) / 64, 256, 0, stream>>>(in_feat, nullptr, spk, out);
    k_edge_gemm<0><<<MAXTILES, 256, 0, stream>>>(in_feat, nullptr, wpk, src, dst, deg,
                                                 perm, tdesc, out);
  }
}

// Round 6
// 398.357 us; speedup vs baseline: 1.9225x; 1.0074x over previous
//
#include <hip/hip_runtime.h>
#include <hip/hip_bf16.h>

// RGCN forward, MI355X. N=100000, E=400000, IN=OUT=256, R=200, B=32.
// Tier A: prep1{wgen|slwpk|hist+feat} -> prep2{etype-scan|deg-blocksums} ->
// prep3{deg-scan, inline prefix} -> prep4{scatter: gsrc/gdst/ginv/dlist} ->
// selfA GEMM (writes out) -> 512-thr edge GEMM (stage-once, 8 waves) writing
// scaled bf16 msg -> LDS-free aggregate (16-lane group per dst, RMW out).

#define NN 100000
#define EE 400000
#define RR 200
#define BB 32
#define MAXTILES 6464   // >= E/64 + R ; divisible by 8
#define SCHUNK 2048
#define NSCAN ((NN + 255) / 256) // 391

typedef __attribute__((ext_vector_type(8))) short short8v;   // 8 x bf16 (16B)
typedef __attribute__((ext_vector_type(4))) float f32x4;

__device__ __forceinline__ unsigned short f2bf(float f) {
  unsigned u = __float_as_uint(f);
  u += 0x7FFF + ((u >> 16) & 1);          // RNE
  return (unsigned short)(u >> 16);
}
__device__ __forceinline__ float bf2f(unsigned short h) {
  return __uint_as_float(((unsigned)h) << 16);
}

// ---------------------------------------------------------------------------
// prep1: blocks [0,800): wgen (L2-blocked W_r pack); [800,832): slwpk;
// [832,1344): etype hist + dst degree + (FEAT) f32->bf16 feature convert.
// W_pk layout per relation: [ct=16][kt=8][lane=64][j=8] bf16 where
//   value = W_r[k = kt*32 + (lane>>4)*8 + j][n = ct*16 + (lane&15)].
template <bool FEAT>
__global__ __launch_bounds__(256) void k_prep1(
    const float* __restrict__ basis, const float* __restrict__ coef,
    const float* __restrict__ slw, const int* __restrict__ etype,
    const int* __restrict__ dst, const float* __restrict__ in_feat,
    short* __restrict__ wpk, short* __restrict__ spk,
    int* __restrict__ hist, int* __restrict__ deg,
    unsigned short* __restrict__ featb) {
  __shared__ int lh[RR];
  int b = blockIdx.x, tid = threadIdx.x;
  if (b < 800) {                       // ---- wgen ----
    int ord = (b & 7) * 100 + (b >> 3);
    int rg = ord % 25;
    int pk8 = (ord / 25) * 256 + tid;
    int lane = pk8 & 63;
    int kt = (pk8 >> 6) & 7;
    int ct = pk8 >> 9;
    int n  = ct * 16 + (lane & 15);
    int k0 = kt * 32 + ((lane >> 4) << 3);
    float acc[8][8];
#pragma unroll
    for (int r = 0; r < 8; ++r)
#pragma unroll
      for (int j = 0; j < 8; ++j) acc[r][j] = 0.f;
    for (int bb = 0; bb < BB; ++bb) {
      float bas[8];
#pragma unroll
      for (int j = 0; j < 8; ++j) bas[j] = basis[bb * 65536 + (k0 + j) * 256 + n];
#pragma unroll
      for (int r = 0; r < 8; ++r) {
        float c = coef[(rg * 8 + r) * BB + bb];
#pragma unroll
        for (int j = 0; j < 8; ++j) acc[r][j] += c * bas[j];
      }
    }
#pragma unroll
    for (int r = 0; r < 8; ++r) {
      short8v v;
#pragma unroll
      for (int j = 0; j < 8; ++j) v[j] = (short)f2bf(acc[r][j]);
      *(short8v*)(wpk + (size_t)(rg * 8 + r) * 65536 + (size_t)pk8 * 8) = v;
    }
    return;
  }
  if (b < 832) {                       // ---- slwpk ----
    int t = (b - 832 + 32) * 256 + tid - 32 * 256;  // = (b-800)*256+tid
    t = (b - 800) * 256 + tid;
    int lane = t & 63;
    int kt = (t >> 6) & 7;
    int ct = t >> 9;
    int n  = ct * 16 + (lane & 15);
    int k0 = kt * 32 + ((lane >> 4) << 3);
    short8v v;
#pragma unroll
    for (int j = 0; j < 8; ++j) v[j] = (short)f2bf(slw[(k0 + j) * 256 + n]);
    *(short8v*)(spk + (size_t)t * 8) = v;
    return;
  }
  // ---- hist + deg + feat ----
  int hb = b - 832;                    // 512 blocks
  for (int i = tid; i < RR; i += 256) lh[i] = 0;
  __syncthreads();
  for (int e = hb * 256 + tid; e < EE; e += 512 * 256) {
    atomicAdd(&lh[etype[e]], 1);
    atomicAdd(&deg[dst[e]], 1);
  }
  if (FEAT) {
    const int total = NN * 64;         // float4 count
    for (int i = hb * 256 + tid; i < total; i += 512 * 256) {
      float4 v = ((const float4*)in_feat)[i];
      ushort4 h;
      h.x = f2bf(v.x); h.y = f2bf(v.y); h.z = f2bf(v.z); h.w = f2bf(v.w);
      ((ushort4*)featb)[i] = h;
    }
  }
  __syncthreads();
  for (int i = tid; i < RR; i += 256)
    if (lh[i]) atomicAdd(&hist[i], lh[i]);
}

// ---------------------------------------------------------------------------
// prep2: block 0: etype-bin scan -> cur + tdesc; blocks 1..391: deg block sums.
__global__ __launch_bounds__(256) void k_prep2(const int* __restrict__ hist,
                                               const int* __restrict__ deg,
                                               int* __restrict__ cur,
                                               int4* __restrict__ tdesc,
                                               int* __restrict__ bsum) {
  __shared__ int h[RR];
  __shared__ int off[RR];
  __shared__ int toff[RR];
  __shared__ int tot;
  __shared__ int ws4[4];
  int b = blockIdx.x, tid = threadIdx.x;
  if (b == 0) {
    for (int i = tid; i < RR; i += 256) h[i] = hist[i];
    __syncthreads();
    if (tid == 0) {
      int s = 0, ts = 0;
      for (int r = 0; r < RR; ++r) {
        off[r] = s; s += h[r];
        toff[r] = ts; ts += (h[r] + 63) >> 6;
      }
      tot = ts;
    }
    __syncthreads();
    if (tid < RR) {
      int r = tid, cnt = h[r], base = off[r], to = toff[r];
      cur[r] = base;
      int nt = (cnt + 63) >> 6;
      for (int t2 = 0; t2 < nt; ++t2)
        tdesc[to + t2] = make_int4(r, base + t2 * 64, min(64, cnt - t2 * 64), 0);
    }
    for (int i = tot + tid; i < MAXTILES; i += 256)
      tdesc[i] = make_int4(0, 0, 0, 0);
    return;
  }
  int i = (b - 1) * 256 + tid;
  int v = (i < NN) ? deg[i] : 0;
#pragma unroll
  for (int d = 32; d; d >>= 1) v += __shfl_down(v, d, 64);
  if ((tid & 63) == 0) ws4[tid >> 6] = v;
  __syncthreads();
  if (tid == 0) bsum[b - 1] = ws4[0] + ws4[1] + ws4[2] + ws4[3];
}

// prep3 (tier A): deg exclusive scan -> row_ptr/cur2; bsum prefix inline.
__global__ __launch_bounds__(256) void k_prep3(const int* __restrict__ deg,
                                               const int* __restrict__ bsum,
                                               int* __restrict__ row_ptr,
                                               int* __restrict__ cur2) {
  __shared__ int ws4[4];
  __shared__ int wo4[4];
  __shared__ int psum[4];
  int tid = threadIdx.x, b = blockIdx.x;
  // prefix of bsum[0..b)
  int sp = 0;
  for (int i = tid; i < b; i += 256) sp += bsum[i];
#pragma unroll
  for (int d = 32; d; d >>= 1) sp += __shfl_down(sp, d, 64);
  if ((tid & 63) == 0) psum[tid >> 6] = sp;
  // local scan of this block's 256 deg values
  int i = b * 256 + tid;
  int v = (i < NN) ? deg[i] : 0;
  int x = v;
#pragma unroll
  for (int d = 1; d < 64; d <<= 1) {
    int y = __shfl_up(x, d, 64);
    if ((tid & 63) >= d) x += y;
  }
  if ((tid & 63) == 63) ws4[tid >> 6] = x;
  __syncthreads();
  if (tid == 0) {
    int s = 0;
    for (int w2 = 0; w2 < 4; ++w2) { wo4[w2] = s; s += ws4[w2]; }
    psum[0] = psum[0] + psum[1] + psum[2] + psum[3];
  }
  __syncthreads();
  int excl = x - v + wo4[tid >> 6] + psum[0];
  if (i < NN) { row_ptr[i] = excl; cur2[i] = excl; }
  if (i == 0 && b == 0) row_ptr[NN] = EE;
}

// prep4: counting-sort scatter; materializes per-position gsrc/gdst/ginv
// (flat metadata for the GEMM) and (DL) dst-CSR value list.
template <bool DL>
__global__ __launch_bounds__(256) void k_prep4(const int* __restrict__ etype,
                                               const int* __restrict__ src,
                                               const int* __restrict__ dst,
                                               const int* __restrict__ deg,
                                               int* __restrict__ cur,
                                               int* __restrict__ gsrc,
                                               int* __restrict__ gdst,
                                               float* __restrict__ ginv,
                                               int* __restrict__ cur2,
                                               int* __restrict__ dlist) {
  __shared__ int lh[RR];
  __shared__ int lbase[RR];
  __shared__ int lcur[RR];
  int tid = threadIdx.x;
  int e0 = blockIdx.x * SCHUNK;
  for (int i = tid; i < RR; i += 256) lh[i] = 0;
  __syncthreads();
  for (int i = tid; i < SCHUNK; i += 256) {
    int e = e0 + i;
    if (e < EE) atomicAdd(&lh[etype[e]], 1);
  }
  __syncthreads();
  for (int i = tid; i < RR; i += 256) {
    int c = lh[i];
    lbase[i] = c ? atomicAdd(&cur[i], c) : 0;
    lcur[i] = 0;
  }
  __syncthreads();
  for (int i = tid; i < SCHUNK; i += 256) {
    int e = e0 + i;
    if (e < EE) {
      int et = etype[e];
      int s = lbase[et] + atomicAdd(&lcur[et], 1);
      int d = dst[e];
      gsrc[s] = src[e];
      gdst[s] = d;
      ginv[s] = 1.0f / (float)max(deg[d], 1);
      if (DL) {
        int pos = atomicAdd(&cur2[d], 1);
        dlist[pos] = s;
      }
    }
  }
}

// ---------------------------------------------------------------------------
// Tier A edge GEMM: 512 threads, 8 waves (wm=2 x wc=4), 64x256 tile staged
// ONCE into swizzled LDS; acc[2][4] (32 AGPR). Flat gsrc/ginv metadata (no
// indirection chain, no metadata barrier). Writes scaled bf16 msg rows.
__global__ __launch_bounds__(512) void k_edge(
    const unsigned short* __restrict__ featb, const short* __restrict__ wpk,
    const int* __restrict__ gsrc, const float* __restrict__ ginv,
    const int4* __restrict__ tdesc, unsigned short* __restrict__ msg) {
  __shared__ __align__(16) char lA[32768];
  __shared__ float lL[64];
  int tid = threadIdx.x, wave = tid >> 6, lane = tid & 63;
  int l15 = lane & 15, lg = lane >> 4;
  int bid = blockIdx.x;
  int tile = (bid & 7) * (MAXTILES / 8) + (bid >> 3);   // XCD-contiguous
  int4 d = tdesc[tile];
  int rows = d.z;
  if (rows <= 0) return;
  int r = d.x, rs = d.y;
  if (tid < 64) lL[tid] = ginv[min(rs + tid, EE - 1)];
  // stage A (row = idx>>5, 16B chunk q = idx&31)
  int srow[4];
#pragma unroll
  for (int u = 0; u < 4; ++u) {
    int idx = u * 512 + tid;
    srow[u] = gsrc[min(rs + (idx >> 5), EE - 1)];
  }
  short8v sv[4];
#pragma unroll
  for (int u = 0; u < 4; ++u) {
    int idx = u * 512 + tid;
    sv[u] = *(const short8v*)(featb + (size_t)srow[u] * 256 + (idx & 31) * 8);
  }
#pragma unroll
  for (int u = 0; u < 4; ++u) {
    int idx = u * 512 + tid;
    int row = idx >> 5, q = idx & 31;
    *(short8v*)(lA + ((row * 512 + q * 16) ^ ((row & 7) << 4))) = sv[u];
  }
  __syncthreads();
  int wm = wave >> 2, wc = wave & 3;
  f32x4 acc[2][4];
#pragma unroll
  for (int m = 0; m < 2; ++m)
#pragma unroll
    for (int c = 0; c < 4; ++c) acc[m][c] = (f32x4){0.f, 0.f, 0.f, 0.f};
  const short* bp = wpk + (size_t)r * 65536 + (size_t)(wc * 4) * 4096 + (size_t)lane * 8;
#pragma unroll
  for (int kt = 0; kt < 8; ++kt) {
    short8v bfr[4], a2[2];
#pragma unroll
    for (int c = 0; c < 4; ++c) bfr[c] = *(const short8v*)(bp + c * 4096 + kt * 512);
#pragma unroll
    for (int m = 0; m < 2; ++m) {
      int row = wm * 32 + m * 16 + l15;
      a2[m] = *(const short8v*)(lA + ((row * 512 + kt * 64 + lg * 16) ^ ((row & 7) << 4)));
    }
#pragma unroll
    for (int m = 0; m < 2; ++m)
#pragma unroll
      for (int c = 0; c < 4; ++c)
        acc[m][c] = __builtin_amdgcn_mfma_f32_16x16x32_bf16(a2[m], bfr[c], acc[m][c], 0, 0, 0);
  }
  __syncthreads();                     // done reading lA
  // scale + repack bf16 via lA
#pragma unroll
  for (int m = 0; m < 2; ++m)
#pragma unroll
    for (int j = 0; j < 4; ++j) {
      int row = wm * 32 + m * 16 + lg * 4 + j;
      float inv = lL[row];
      int rb = row * 512, sw = (row & 7) << 4;
#pragma unroll
      for (int c = 0; c < 4; ++c) {
        int col = wc * 64 + c * 16 + l15;
        *(unsigned short*)(lA + ((rb + col * 2) ^ sw)) = f2bf(acc[m][c][j] * inv);
      }
    }
  __syncthreads();
#pragma unroll
  for (int u = 0; u < 4; ++u) {
    int idx = u * 512 + tid;
    int row = idx >> 5, q = idx & 31;
    if (row < rows) {
      short8v vv = *(const short8v*)(lA + ((row * 512 + q * 16) ^ ((row & 7) << 4)));
      *(short8v*)(msg + (size_t)(rs + row) * 256 + q * 8) = vv;
    }
  }
}

// ---------------------------------------------------------------------------
// Tier A self-loop GEMM: out[n] = featb[n] @ slw (f32 out, direct store).
__global__ __launch_bounds__(256) void k_selfA(const unsigned short* __restrict__ featb,
                                               const short* __restrict__ spk,
                                               float* __restrict__ out) {
  __shared__ __align__(16) char lA[32768];
  int tid = threadIdx.x, wave = tid >> 6, lane = tid & 63;
  int l15 = lane & 15, lg = lane >> 4;
  int n0 = blockIdx.x * 64;
  short8v sv[8];
#pragma unroll
  for (int u = 0; u < 8; ++u) {
    int idx = u * 256 + tid;
    int row = idx >> 5, q = idx & 31;
    int n = min(n0 + row, NN - 1);
    sv[u] = *(const short8v*)(featb + (size_t)n * 256 + q * 8);
  }
#pragma unroll
  for (int u = 0; u < 8; ++u) {
    int idx = u * 256 + tid;
    int row = idx >> 5, q = idx & 31;
    *(short8v*)(lA + ((row * 512 + q * 16) ^ ((row & 7) << 4))) = sv[u];
  }
  __syncthreads();
  f32x4 acc[4][4];
#pragma unroll
  for (int m = 0; m < 4; ++m)
#pragma unroll
    for (int c = 0; c < 4; ++c) acc[m][c] = (f32x4){0.f, 0.f, 0.f, 0.f};
  const short* bp = spk + (size_t)wave * 4 * 4096 + (size_t)lane * 8;
#pragma unroll
  for (int kt = 0; kt < 8; ++kt) {
    short8v a[4], b[4];
#pragma unroll
    for (int c = 0; c < 4; ++c) b[c] = *(const short8v*)(bp + c * 4096 + kt * 512);
#pragma unroll
    for (int m = 0; m < 4; ++m) {
      int row = m * 16 + l15;
      a[m] = *(const short8v*)(lA + ((row * 512 + kt * 64 + lg * 16) ^ ((row & 7) << 4)));
    }
#pragma unroll
    for (int m = 0; m < 4; ++m)
#pragma unroll
      for (int c = 0; c < 4; ++c)
        acc[m][c] = __builtin_amdgcn_mfma_f32_16x16x32_bf16(a[m], b[c], acc[m][c], 0, 0, 0);
  }
#pragma unroll
  for (int m = 0; m < 4; ++m)
#pragma unroll
    for (int j = 0; j < 4; ++j) {
      int n = n0 + m * 16 + lg * 4 + j;
      if (n < NN) {
        float* op = out + (size_t)n * 256 + wave * 64 + l15;
#pragma unroll
        for (int c = 0; c < 4; ++c) op[c * 16] = acc[m][c][j];
      }
    }
}

// ---------------------------------------------------------------------------
// Tier A aggregate: LDS-free; one 16-lane group per dst node. msg rows are
// pre-scaled -> plain sum; RMW of out (holds self-loop term).
__global__ __launch_bounds__(256) void k_aggregate(
    const unsigned short* __restrict__ msg, const int* __restrict__ row_ptr,
    const int* __restrict__ dlist, float* __restrict__ out) {
  int g = blockIdx.x * 16 + (threadIdx.x >> 4);
  if (g >= NN) return;
  int gl = threadIdx.x & 15;
  int gw = (threadIdx.x >> 4) & 3;           // group index within wave
  int lo = row_ptr[g], hi = row_ptr[g + 1];
  if (lo >= hi) return;
  float a[16];
#pragma unroll
  for (int k = 0; k < 16; ++k) a[k] = 0.f;
  for (int q0 = lo; q0 < hi; q0 += 16) {
    int pv = (q0 + gl < hi) ? dlist[q0 + gl] : 0;
    int qm = min(16, hi - q0);
    for (int j = 0; j < qm; ++j) {
      int p = __shfl(pv, gw * 16 + j, 64);
      const unsigned short* mp = msg + (size_t)p * 256 + gl * 16;
      short8v m0 = *(const short8v*)mp;
      short8v m1 = *(const short8v*)(mp + 8);
#pragma unroll
      for (int k = 0; k < 8; ++k) {
        a[k]     += bf2f((unsigned short)m0[k]);
        a[k + 8] += bf2f((unsigned short)m1[k]);
      }
    }
  }
  float* op = out + (size_t)g * 256 + gl * 16;
#pragma unroll
  for (int c = 0; c < 4; ++c) {
    f32x4 o = *(const f32x4*)(op + c * 4);
    o[0] += a[c * 4]; o[1] += a[c * 4 + 1]; o[2] += a[c * 4 + 2]; o[3] += a[c * 4 + 3];
    *(f32x4*)(op + c * 4) = o;
  }
}

// ---------------------------------------------------------------------------
// Tier B/C fallbacks (atomic epilogue), using flat gsrc/gdst/ginv metadata.
__device__ __forceinline__ void gemm64(const char* lA, const short* __restrict__ wpk,
                                       f32x4 acc[4][4], int wave, int lane) {
  int l15 = lane & 15, lg = lane >> 4;
  const short* bp = wpk + (size_t)wave * 4 * 4096 + (size_t)lane * 8;
#pragma unroll
  for (int kt = 0; kt < 8; ++kt) {
    short8v a[4], b[4];
#pragma unroll
    for (int c = 0; c < 4; ++c) b[c] = *(const short8v*)(bp + c * 4096 + kt * 512);
#pragma unroll
    for (int m = 0; m < 4; ++m) {
      int row = m * 16 + l15;
      a[m] = *(const short8v*)(lA + ((row * 512 + kt * 64 + lg * 16) ^ ((row & 7) << 4)));
    }
#pragma unroll
    for (int m = 0; m < 4; ++m)
#pragma unroll
      for (int c = 0; c < 4; ++c)
        acc[m][c] = __builtin_amdgcn_mfma_f32_16x16x32_bf16(a[m], b[c], acc[m][c], 0, 0, 0);
  }
}

template <bool B16>
__global__ __launch_bounds__(256) void k_self_gemm(const float* __restrict__ in_feat,
                                                   const unsigned short* __restrict__ featb,
                                                   const short* __restrict__ spk,
                                                   float* __restrict__ out) {
  __shared__ __align__(16) char lA[32768];
  int n0 = blockIdx.x * 64;
  int tid = threadIdx.x;
  if (B16) {
    short8v sv[8];
#pragma unroll
    for (int u = 0; u < 8; ++u) {
      int idx = u * 256 + tid;
      int row = idx >> 5, q = idx & 31;
      int n = min(n0 + row, NN - 1);
      sv[u] = *(const short8v*)(featb + (size_t)n * 256 + q * 8);
    }
#pragma unroll
    for (int u = 0; u < 8; ++u) {
      int idx = u * 256 + tid;
      int row = idx >> 5, q = idx & 31;
      *(short8v*)(lA + ((row * 512 + q * 16) ^ ((row & 7) << 4))) = sv[u];
    }
  } else {
#pragma unroll
    for (int half = 0; half < 2; ++half) {
      float4 v[8];
#pragma unroll
      for (int u = 0; u < 8; ++u) {
        int it = half * 2048 + u * 256 + tid;
        int row = it >> 6, q = it & 63;
        int n = n0 + row;
        v[u] = (n < NN) ? ((const float4*)(in_feat + (size_t)n * 256))[q]
                        : make_float4(0.f, 0.f, 0.f, 0.f);
      }
#pragma unroll
      for (int u = 0; u < 8; ++u) {
        int it = half * 2048 + u * 256 + tid;
        int row = it >> 6, q = it & 63;
        ushort4 hh;
        hh.x = f2bf(v[u].x); hh.y = f2bf(v[u].y); hh.z = f2bf(v[u].z); hh.w = f2bf(v[u].w);
        *(ushort4*)(lA + ((row * 512 + q * 8) ^ ((row & 7) << 4))) = hh;
      }
    }
  }
  __syncthreads();
  f32x4 acc[4][4];
#pragma unroll
  for (int m = 0; m < 4; ++m)
#pragma unroll
    for (int c = 0; c < 4; ++c) acc[m][c] = (f32x4){0.f, 0.f, 0.f, 0.f};
  int wave = tid >> 6, lane = tid & 63;
  gemm64(lA, spk, acc, wave, lane);
  int l15 = lane & 15, lg = lane >> 4;
#pragma unroll
  for (int m = 0; m < 4; ++m)
#pragma unroll
    for (int j = 0; j < 4; ++j) {
      int n = n0 + m * 16 + lg * 4 + j;
      if (n < NN) {
        float* op = out + (size_t)n * 256 + wave * 64 + l15;
#pragma unroll
        for (int c = 0; c < 4; ++c) op[c * 16] = acc[m][c][j];
      }
    }
}

template <int MODE>   // 0: f32 feat, 1: bf16 feat; atomic mean-scatter into out
__global__ __launch_bounds__(256) void k_edge_gemmBC(const float* __restrict__ in_feat,
                                                     const unsigned short* __restrict__ featb,
                                                     const short* __restrict__ wpk,
                                                     const int* __restrict__ gsrc,
                                                     const int* __restrict__ gdst,
                                                     const float* __restrict__ ginv,
                                                     const int4* __restrict__ tdesc,
                                                     float* __restrict__ out) {
  __shared__ __align__(16) char lA[32768];
  __shared__ int lsrc[64];
  __shared__ int ldst[64];
  __shared__ float linv[64];
  int bid = blockIdx.x;
  int tile = (bid & 7) * (MAXTILES / 8) + (bid >> 3);
  int4 d = tdesc[tile];
  int rows = d.z;
  if (rows <= 0) return;
  int r = d.x, rs = d.y;
  int tid = threadIdx.x;
  if (tid < 64) {
    if (tid < rows) {
      lsrc[tid] = gsrc[rs + tid];
      ldst[tid] = gdst[rs + tid];
      linv[tid] = ginv[rs + tid];
    } else {
      lsrc[tid] = -1; ldst[tid] = -1; linv[tid] = 0.f;
    }
  }
  __syncthreads();
  if (MODE == 1) {
    short8v sv[8];
#pragma unroll
    for (int u = 0; u < 8; ++u) {
      int idx = u * 256 + tid;
      int row = idx >> 5, q = idx & 31;
      int s = lsrc[row];
      sv[u] = (s >= 0) ? *(const short8v*)(featb + (size_t)s * 256 + q * 8)
                       : (short8v){0, 0, 0, 0, 0, 0, 0, 0};
    }
#pragma unroll
    for (int u = 0; u < 8; ++u) {
      int idx = u * 256 + tid;
      int row = idx >> 5, q = idx & 31;
      *(short8v*)(lA + ((row * 512 + q * 16) ^ ((row & 7) << 4))) = sv[u];
    }
  } else {
#pragma unroll
    for (int half = 0; half < 2; ++half) {
      float4 v[8];
#pragma unroll
      for (int u = 0; u < 8; ++u) {
        int it = half * 2048 + u * 256 + tid;
        int row = it >> 6, q = it & 63;
        int s = lsrc[row];
        v[u] = (s >= 0) ? ((const float4*)(in_feat + (size_t)s * 256))[q]
                        : make_float4(0.f, 0.f, 0.f, 0.f);
      }
#pragma unroll
      for (int u = 0; u < 8; ++u) {
        int it = half * 2048 + u * 256 + tid;
        int row = it >> 6, q = it & 63;
        ushort4 hh;
        hh.x = f2bf(v[u].x); hh.y = f2bf(v[u].y); hh.z = f2bf(v[u].z); hh.w = f2bf(v[u].w);
        *(ushort4*)(lA + ((row * 512 + q * 8) ^ ((row & 7) << 4))) = hh;
      }
    }
  }
  __syncthreads();
  f32x4 acc[4][4];
#pragma unroll
  for (int m = 0; m < 4; ++m)
#pragma unroll
    for (int c = 0; c < 4; ++c) acc[m][c] = (f32x4){0.f, 0.f, 0.f, 0.f};
  int wave = tid >> 6, lane = tid & 63;
  gemm64(lA, wpk + (size_t)r * 65536, acc, wave, lane);
  int l15 = lane & 15, lg = lane >> 4;
#pragma unroll
  for (int m = 0; m < 4; ++m)
#pragma unroll
    for (int j = 0; j < 4; ++j) {
      int row = m * 16 + lg * 4 + j;
      int dd = ldst[row];
      if (dd >= 0) {
        float inv = linv[row];
        float* op = out + (size_t)dd * 256 + wave * 64 + l15;
#pragma unroll
        for (int c = 0; c < 4; ++c) unsafeAtomicAdd(op + c * 16, acc[m][c][j] * inv);
      }
    }
}

// ---------------------------------------------------------------------------
extern "C" void kernel_launch(void* const* d_in, const int* in_sizes, int n_in,
                              void* d_out, int out_size, void* d_ws, size_t ws_size,
                              hipStream_t stream) {
  const float* in_feat = (const float*)d_in[0];
  const float* basis   = (const float*)d_in[1];
  const float* coef    = (const float*)d_in[2];
  const float* slw     = (const float*)d_in[3];
  const int*   src     = (const int*)d_in[4];
  const int*   dst     = (const int*)d_in[5];
  const int*   etype   = (const int*)d_in[6];
  float* out = (float*)d_out;

  char* base = (char*)d_ws;
  char* w = base;
  auto alloc = [&](size_t bytes) {
    char* p = w;
    w += (bytes + 255) & ~(size_t)255;
    return p;
  };
  // base group (tiers B/C)
  short* wpk  = (short*)alloc((size_t)RR * 65536 * 2);   // 26.2 MB
  short* spk  = (short*)alloc(65536 * 2);
  int*   gsrc = (int*)alloc((size_t)EE * 4);
  int*   gdst = (int*)alloc((size_t)EE * 4);
  float* ginv = (float*)alloc((size_t)EE * 4);
  int*   deg  = (int*)alloc((size_t)NN * 4);
  int*   hist = (int*)alloc(RR * 4);
  int*   cur  = (int*)alloc(RR * 4);
  int4*  tdesc = (int4*)alloc((size_t)MAXTILES * 16);
  int*   bsum = (int*)alloc(NSCAN * 4);
  // tier B adds bf16 feat
  unsigned short* featb = (unsigned short*)alloc((size_t)NN * 256 * 2);  // 51.2 MB
  size_t need_b = (size_t)(w - base);
  // tier A adds dst-CSR + msg buffer
  int* row_ptr = (int*)alloc((size_t)(NN + 1) * 4);
  int* cur2    = (int*)alloc((size_t)NN * 4);
  int* dlist   = (int*)alloc((size_t)EE * 4);
  unsigned short* msg = (unsigned short*)alloc((size_t)EE * 256 * 2);    // 204.8 MB
  size_t need_a = (size_t)(w - base);

  bool tierA = ws_size >= need_a;
  bool tierB = ws_size >= need_b;

  hipMemsetAsync(hist, 0, RR * 4, stream);
  hipMemsetAsync(deg, 0, (size_t)NN * 4, stream);

  if (tierA) {
    k_prep1<true><<<1344, 256, 0, stream>>>(basis, coef, slw, etype, dst, in_feat,
                                            wpk, spk, hist, deg, featb);
    k_prep2<<<NSCAN + 1, 256, 0, stream>>>(hist, deg, cur, tdesc, bsum);
    k_prep3<<<NSCAN, 256, 0, stream>>>(deg, bsum, row_ptr, cur2);
    k_prep4<true><<<(EE + SCHUNK - 1) / SCHUNK, 256, 0, stream>>>(
        etype, src, dst, deg, cur, gsrc, gdst, ginv, cur2, dlist);
    k_selfA<<<(NN + 63) / 64, 256, 0, stream>>>(featb, spk, out);
    k_edge<<<MAXTILES, 512, 0, stream>>>(featb, wpk, gsrc, ginv, tdesc, msg);
    k_aggregate<<<(NN + 15) / 16, 256, 0, stream>>>(msg, row_ptr, dlist, out);
  } else if (tierB) {
    k_prep1<true><<<1344, 256, 0, stream>>>(basis, coef, slw, etype, dst, in_feat,
                                            wpk, spk, hist, deg, featb);
    k_prep2<<<NSCAN + 1, 256, 0, stream>>>(hist, deg, cur, tdesc, bsum);
    k_prep4<false><<<(EE + SCHUNK - 1) / SCHUNK, 256, 0, stream>>>(
        etype, src, dst, deg, cur, gsrc, gdst, ginv, nullptr, nullptr);
    k_self_gemm<true><<<(NN + 63) / 64, 256, 0, stream>>>(in_feat, featb, spk, out);
    k_edge_gemmBC<1><<<MAXTILES, 256, 0, stream>>>(in_feat, featb, wpk, gsrc, gdst,
                                                   ginv, tdesc, out);
  } else {
    k_prep1<false><<<1344, 256, 0, stream>>>(basis, coef, slw, etype, dst, in_feat,
                                             wpk, spk, hist, deg, nullptr);
    k_prep2<<<NSCAN + 1, 256, 0, stream>>>(hist, deg, cur, tdesc, bsum);
    k_prep4<false><<<(EE + SCHUNK - 1) / SCHUNK, 256, 0, stream>>>(
        etype, src, dst, deg, cur, gsrc, gdst, ginv, nullptr, nullptr);
    k_self_gemm<false><<<(NN + 63) / 64, 256, 0, stream>>>(in_feat, nullptr, spk, out);
    k_edge_gemmBC<0><<<MAXTILES, 256, 0, stream>>>(in_feat, nullptr, wpk, gsrc, gdst,
                                                   ginv, tdesc, out);
  }
}